// Round 6
// baseline (526.235 us; speedup 1.0000x reference)
//
#include <hip/hip_runtime.h>
#include <stdint.h>

// VQ: z [32,256,32,32] f32, embedding [8192,256] f32.
// N = 32768 rows, d = 256, K = 8192 codes.
// out = [ z_q (8388608 f32, [b,c,h,w]) | diff (1 f32) | idx (32768 f32) ]
//
// R6: 32x32x16 MFMA, wave tile 32 rows x 64 codes, A resident (64 VGPR),
// B streamed (shared by all 4 waves -> L1 broadcast), 3 waves/SIMD, zero
// LDS/barriers in the GEMM. Fragment layout re-blocked to 32 rows.
//
// Fragment layout for X[rows][256] f16 (rows % 32 == 0):
//   off_halves(row,k) = (row>>5)*8192 + ((k>>3)*32 + (row&31))*8 + (k&7)
// Wave A-load (kstep): base + kstep*512 + lane*8 -> contiguous 1 KB.
// 32x32x16 A operand: lane l holds A[row=l&31][k=kstep*16+(l>>5)*8+h]  -> matches.
// C/D layout: col = lane&31, row = (reg&3) + 8*(reg>>2) + 4*(lane>>5).
//
// Workspace (bytes):
//   z_hi frag [32768][256] f16 @ 0         (16777216)
//   e_hi frag [8192][256]  f16 @ 16777216  (4194304)
//   e_norm    [8192]       f32 @ 20971520  (32768)
//   cand      [32768][16]  u32 @ 21004288  (2097152)   total 23101440

typedef _Float16 half8 __attribute__((ext_vector_type(8)));
typedef float floatx4 __attribute__((ext_vector_type(4)));
typedef float floatx16 __attribute__((ext_vector_type(16)));

#define BETA 0.25f

__device__ __forceinline__ void pin(half8& x) { asm volatile("" : "+v"(x)); }

// ---------------- split z: [b,c,hw] f32 -> zh 32-row fragment order --------
__global__ __launch_bounds__(256) void split_z_t(const float* __restrict__ z,
                                                 _Float16* __restrict__ zh) {
  __shared__ float tile[64][65];  // [c local][hw local], +1 pad
  int bt = blockIdx.x;       // 2048 blocks: 512 n-tiles x 4 c-tiles
  int ct = bt & 3;
  int ntile = bt >> 2;
  int b = ntile >> 4;
  int hw0 = (ntile & 15) * 64;
  int c0 = ct * 64;
  int t = threadIdx.x;
  int tr = t >> 6, tc = t & 63;
#pragma unroll
  for (int i = 0; i < 16; ++i) {
    int c = tr + i * 4;
    tile[c][tc] = z[b * 262144 + (c0 + c) * 1024 + hw0 + tc];  // coalesced
  }
  __syncthreads();
  int n0abs = b * 1024 + hw0;  // multiple of 64
  int rb = t >> 7;             // 0/1: which 32-row block
  int jb = t & 127;
  size_t base = (size_t)((n0abs >> 5) + rb) * 8192 + (size_t)(c0 >> 3) * 256;
#pragma unroll
  for (int iter = 0; iter < 2; ++iter) {
    int j = jb + iter * 128;   // 0..255: j = k8l*32 + r
    int r = j & 31, k8l = j >> 5;
    half8 hv;
#pragma unroll
    for (int h = 0; h < 8; ++h) hv[h] = (_Float16)tile[k8l * 8 + h][rb * 32 + r];
    *(half8*)&zh[base + (size_t)j * 8] = hv;  // consecutive t -> contiguous 16B
  }
}

// ---------------- split e -> eh 32-row fragment order + ||e||^2 ------------
__global__ __launch_bounds__(256) void split_e(const float* __restrict__ e,
                                               _Float16* __restrict__ eh,
                                               float* __restrict__ en) {
  __shared__ float el[32][257];  // 32.9 KB
  int k0 = blockIdx.x * 32;
  int t = threadIdx.x;
#pragma unroll
  for (int r8 = 0; r8 < 32; ++r8) el[r8][t] = e[(k0 + r8) * 256 + t];
  __syncthreads();
  {
    int r = t >> 3, li = t & 7;
    float s = 0.f;
#pragma unroll
    for (int j = 0; j < 32; ++j) {
      float v = el[r][li + 8 * j];
      s += v * v;
    }
#pragma unroll
    for (int st = 1; st < 8; st <<= 1) s += __shfl_xor(s, st);
    if (li == 0) en[k0 + r] = s;
  }
  size_t base = (size_t)(k0 >> 5) * 8192;
#pragma unroll
  for (int iter = 0; iter < 4; ++iter) {
    int j = iter * 256 + t;    // 0..1023: j = k8*32 + r
    int r = j & 31, k8 = j >> 5;
    half8 hv;
#pragma unroll
    for (int h = 0; h < 8; ++h) hv[h] = (_Float16)el[r][k8 * 8 + h];
    *(half8*)&eh[base + (size_t)j * 8] = hv;
  }
}

// ---------------- coarse GEMM: reg-A, streamed shared-B, no barriers ------
// grid (256 n-tiles, 4 kgroups), block 256 = 4 waves, wave = 32 rows.
__global__ __launch_bounds__(256, 3) void vq_coarse(
    const _Float16* __restrict__ zh, const _Float16* __restrict__ eh,
    const float* __restrict__ en_, unsigned* __restrict__ cand) {
  const int tid = threadIdx.x;
  const int l = tid & 63;
  const int w = tid >> 6;
  const int n0 = blockIdx.x * 128;
  const int kbase = blockIdx.y * 2048;
  const int c32 = l & 31;   // code col within tile / also A row
  const int h32 = l >> 5;   // lane half

  // A resident: 32 rows x 256 K = 16 half8 = 64 VGPR, pinned.
  const size_t abase = (size_t)(blockIdx.x * 4 + w) * 8192 + (size_t)l * 8;
  half8 A[16];
#pragma unroll
  for (int ks = 0; ks < 16; ++ks) {
    A[ks] = *(const half8*)&zh[abase + ks * 512];
    pin(A[ks]);
  }

  unsigned p1[16], p2[16];
#pragma unroll
  for (int s = 0; s < 16; ++s) { p1[s] = 0xFFFFFFFFu; p2[s] = 0xFFFFFFFFu; }

  for (int ct = 0; ct < 32; ++ct) {   // 2048 codes, 64 per ct
    const int krow0 = kbase + ct * 64;
    // early env loads (decouple from top-2 use)
    float env0 = en_[krow0 + c32];
    float env1 = en_[krow0 + 32 + c32];
    const size_t bbase = (size_t)(krow0 >> 5) * 8192 + (size_t)l * 8;
    floatx16 acc0 = {};
    floatx16 acc1 = {};
#pragma unroll
    for (int ks = 0; ks < 16; ++ks) {
      half8 b0 = *(const half8*)&eh[bbase + ks * 512];
      half8 b1 = *(const half8*)&eh[bbase + 8192 + ks * 512];
      acc0 = __builtin_amdgcn_mfma_f32_32x32x16_f16(A[ks], b0, acc0, 0, 0, 0);
      acc1 = __builtin_amdgcn_mfma_f32_32x32x16_f16(A[ks], b1, acc1, 0, 0, 0);
    }
    // top-2 update: d = ||e||^2 - 2*dot > 0 on this data -> positive-float
    // bits are uint-monotone; key = (bits & ~1023) | loc.
    unsigned loc0 = (unsigned)((ct & 15) * 64 + c32);
    unsigned loc1 = loc0 + 32;
#pragma unroll
    for (int r = 0; r < 16; ++r) {
      float d0 = fmaf(-2.0f, acc0[r], env0);
      unsigned ck = (__float_as_uint(d0) & 0xFFFFFC00u) | loc0;
      unsigned mn = min(p1[r], ck);
      unsigned mx = max(p1[r], ck);
      p1[r] = mn;
      p2[r] = min(p2[r], mx);
      float d1 = fmaf(-2.0f, acc1[r], env1);
      ck = (__float_as_uint(d1) & 0xFFFFFC00u) | loc1;
      mn = min(p1[r], ck);
      mx = max(p1[r], ck);
      p1[r] = mn;
      p2[r] = min(p2[r], mx);
    }
    if ((ct & 15) == 15) {  // 1024-code group done: merge + emit (no LDS!)
      const int gi = blockIdx.y * 2 + (ct >> 4);
#pragma unroll
      for (int s = 0; s < 16; ++s) {
        unsigned a1 = p1[s], a2 = p2[s];
#pragma unroll
        for (int t2 = 1; t2 < 32; t2 <<= 1) {  // reduce over 32 code lanes
          unsigned b1 = __shfl_xor(a1, t2);
          unsigned b2 = __shfl_xor(a2, t2);
          unsigned m1 = min(a1, b1);
          unsigned M = max(a1, b1);
          a1 = m1;
          a2 = min(min(a2, b2), M);
        }
        if (c32 == 0) {  // lanes 0 and 32 own disjoint row sets
          int row = (s & 3) + 8 * (s >> 2) + 4 * h32;
          int n = n0 + w * 32 + row;
          unsigned long long packed = ((unsigned long long)a2 << 32) | a1;
          *(unsigned long long*)&cand[(size_t)n * 16 + gi * 2] = packed;
        }
        p1[s] = 0xFFFFFFFFu;
        p2[s] = 0xFFFFFFFFu;
      }
    }
  }
}

// -------- refine: in-block z transpose, exact fp64 pick, fused z_q --------
// grid 1024 blocks x 256 thr; block handles 32 rows (same b, hw0..hw0+31).
__global__ __launch_bounds__(256) void vq_refine(const unsigned* __restrict__ cand,
                                                 const float* __restrict__ emb,
                                                 const float* __restrict__ z,
                                                 float* __restrict__ out_idx,
                                                 float* __restrict__ zq,
                                                 float* __restrict__ diff) {
  __shared__ float ztl[32][260];  // 33.3 KB
  __shared__ unsigned win_s[32];
  __shared__ float dsh[4];
  const int t = threadIdx.x;
  const int n0 = blockIdx.x * 32;
  const int b = n0 >> 10;
  const int hw0 = n0 & 1023;
  const int j = t & 31, c8 = t >> 5;
#pragma unroll
  for (int ci = 0; ci < 32; ++ci) {
    int c = ci * 8 + c8;
    ztl[j][c] = z[b * 262144 + c * 1024 + hw0 + j];
  }
  __syncthreads();
  const int w = t >> 6, l = t & 63;
  double wsum = 0.0;
  for (int i = 0; i < 8; ++i) {
    int row = w * 8 + i;
    int n = n0 + row;
    floatx4 zv = *(const floatx4*)&ztl[row][4 * l];
    unsigned ks[16];
    double s[16];
#pragma unroll
    for (int jj = 0; jj < 16; ++jj) {
      unsigned cv = cand[(size_t)n * 16 + jj];
      unsigned k = (unsigned)(jj >> 1) * 1024 + (cv & 1023);
      ks[jj] = k;
      floatx4 ev = *(const floatx4*)&emb[(size_t)k * 256 + l * 4];
      double acc = 0.0;
#pragma unroll
      for (int x = 0; x < 4; ++x) {
        double dd = (double)ev[x] - (double)zv[x];
        acc += dd * dd;
      }
      s[jj] = acc;
    }
#pragma unroll
    for (int jj = 0; jj < 16; ++jj)
#pragma unroll
      for (int st = 1; st < 64; st <<= 1) s[jj] += __shfl_xor(s[jj], st);
    double bestd = 1e300;
    unsigned bestk = 0xffffffffu;
#pragma unroll
    for (int jj = 0; jj < 16; ++jj) {
      if (s[jj] < bestd || (s[jj] == bestd && ks[jj] < bestk)) {
        bestd = s[jj];
        bestk = ks[jj];
      }
    }
    if (l == 0) {
      out_idx[n] = (float)bestk;
      win_s[row] = bestk;
    }
    wsum += bestd;
  }
  if (l == 0) dsh[w] = (float)(wsum * ((double)BETA / 8388608.0));
  __syncthreads();
  if (t == 0) atomicAdd(diff, dsh[0] + dsh[1] + dsh[2] + dsh[3]);
#pragma unroll
  for (int ci = 0; ci < 32; ++ci) {
    int c = ci * 8 + c8;
    zq[b * 262144 + c * 1024 + hw0 + j] = emb[(size_t)win_s[j] * 256 + c];
  }
}

extern "C" void kernel_launch(void* const* d_in, const int* in_sizes, int n_in,
                              void* d_out, int out_size, void* d_ws, size_t ws_size,
                              hipStream_t stream) {
  const float* z = (const float*)d_in[0];
  const float* emb = (const float*)d_in[1];
  char* ws = (char*)d_ws;
  _Float16* zh = (_Float16*)(ws);
  _Float16* eh = (_Float16*)(ws + 16777216);
  float* en = (float*)(ws + 20971520);
  unsigned* cand = (unsigned*)(ws + 21004288);

  float* out = (float*)d_out;
  float* out_zq = out;               // 8388608
  float* out_diff = out + 8388608;   // 1
  float* out_idx = out + 8388609;    // 32768

  hipMemsetAsync(out_diff, 0, 4, stream);

  split_z_t<<<2048, 256, 0, stream>>>(z, zh);
  split_e<<<256, 256, 0, stream>>>(emb, eh, en);
  vq_coarse<<<dim3(256, 4), 256, 0, stream>>>(zh, eh, en, cand);
  vq_refine<<<1024, 256, 0, stream>>>(cand, emb, z, out_idx, out_zq, out_diff);
}